// Round 5
// baseline (431.860 us; speedup 1.0000x reference)
//
#include <hip/hip_runtime.h>
#include <hip/hip_bf16.h>
#include <math.h>

#define B_N 8192
#define T_N 4
#define D_N 1024
#define NB  32                 // 8192/256 row/col blocks
#define NT  16                 // 1024/64 K-tiles
#define TRI (NB * (NB + 1) / 2)  // 528 upper-triangle blocks per view (528 = 8*66)

typedef __bf16 bf16x8 __attribute__((ext_vector_type(8)));
typedef float f32x4 __attribute__((ext_vector_type(4)));

// ---- order-preserving float <-> uint map ----
__device__ inline unsigned int f2u_ord(float f) {
    unsigned int b = __float_as_uint(f);
    return (b & 0x80000000u) ? ~b : (b | 0x80000000u);
}
__device__ inline float u2f_ord(unsigned int u) {
    unsigned int b = (u & 0x80000000u) ? (u & 0x7FFFFFFFu) : ~u;
    return __uint_as_float(b);
}

// round-to-nearest-even f32 -> bf16
__device__ inline unsigned short f2bf(float f) {
    unsigned int u = __float_as_uint(f);
    unsigned int r = (u + 0x7FFFu + ((u >> 16) & 1u)) >> 16;
    return (unsigned short)r;
}

__global__ __launch_bounds__(256) void init_rowmax_kernel(unsigned int* __restrict__ rowmax) {
    int i = blockIdx.x * 256 + threadIdx.x;
    if (i < T_N * B_N) rowmax[i] = 0u;
}

// in: [B][T][D] f32 ; out xn: [T][B][D] bf16 (normalized rows)
__global__ __launch_bounds__(256) void norm_kernel(const float* __restrict__ in,
                                                   unsigned short* __restrict__ xn) {
    const int row  = blockIdx.x * 4 + (threadIdx.x >> 6);
    const int lane = threadIdx.x & 63;
    const int b = row >> 2;
    const int t = row & 3;
    const float* src = in + (size_t)row * D_N;

    float4 v[4];
    float ss = 0.f;
#pragma unroll
    for (int i = 0; i < 4; ++i) {
        v[i] = reinterpret_cast<const float4*>(src)[lane + 64 * i];
        ss += v[i].x * v[i].x + v[i].y * v[i].y + v[i].z * v[i].z + v[i].w * v[i].w;
    }
#pragma unroll
    for (int off = 32; off; off >>= 1) ss += __shfl_xor(ss, off, 64);
    const float rn = 1.0f / fmaxf(sqrtf(ss), 1e-12f);

    unsigned short* dst = xn + ((size_t)t * B_N + b) * D_N;
#pragma unroll
    for (int i = 0; i < 4; ++i) {
        ushort4 o;
        o.x = f2bf(v[i].x * rn);
        o.y = f2bf(v[i].y * rn);
        o.z = f2bf(v[i].z * rn);
        o.w = f2bf(v[i].w * rn);
        reinterpret_cast<ushort4*>(dst)[lane + 64 * i] = o;
    }
}

#define GLOAD_LDS16(g, l)                                                              \
    __builtin_amdgcn_global_load_lds(                                                  \
        (const __attribute__((address_space(1))) unsigned int*)(g),                    \
        (__attribute__((address_space(3))) unsigned int*)(l), 16, 0, 0)

// Gram matrix upper-triangle, 256x256 tile, BK=64, 8 waves (2M x 4N).
// 3-phase fragment-retention schedule per K-tile:
//   P1: read A0(8)+B0(4), stage u0,u2(next), 16 MFMA (0,0)
//   P2: read B1(4),                         16 MFMA (0,1), gate vmcnt(4)
//   P3: read A1(8), stage u3,u1(next),      32 MFMA (1,0)+(1,1), gate vmcnt(4)
// Gates retire units issued >=3 phases earlier (wave-local ledger verified).
// LDS chunk-XOR swizzle (chunk ^= row&7), source-side pre-swizzle for the
// linear global_load_lds dest + identical read-side swizzle.
__global__ __launch_bounds__(512, 2) void gemm_rowmax_kernel(const unsigned short* __restrict__ xn,
                                                             unsigned int* __restrict__ rowmax) {
    const int t = blockIdx.z;
    // XCD-chunked bijective swizzle: 528 = 8 * 66; consecutive triangle ids
    // (sharing the A row-panel) land on the SAME XCD's L2.
    const int bid = blockIdx.x;
    int l = (bid & 7) * (TRI / 8) + (bid >> 3);
    // triangle decode: linear -> (by, bx), bx >= by
    int by = 0;
    while (l >= NB - by) { l -= NB - by; ++by; }
    const int bx = by + l;

    const unsigned short* X = xn + (size_t)t * B_N * D_N;

    __shared__ __align__(16) unsigned short lds[65536];  // 128 KiB: [2 buf][A 16K el | B 16K el]

    const int tid  = threadIdx.x;
    const int lane = tid & 63;
    const int wv   = tid >> 6;   // 0..7
    const int wr   = wv >> 2;    // M half (128 rows)
    const int wcn  = wv & 3;     // N quarter (64 cols)

    // staging: wave-load = 8 rows x 8 chunks(16B); source chunk pre-swizzled
    const int lrow8  = lane >> 3;
    const int gchunk = (lane & 7) ^ lrow8;
    const size_t aGR = (size_t)by * 256;
    const size_t bGR = (size_t)bx * 256;
    const int idx0 = wv * 2, idx1 = wv * 2 + 1;
    const int rB0 = (idx0 >> 2) * 64 + (idx0 & 3) * 8;
    const int rB1 = (idx1 >> 2) * 64 + (idx1 & 3) * 8;

    // fragment read bases; read-side swizzle: chunk = kk ^ (row&7), row&7 == lane&7
    const int arBase = wr * 128 + (lane & 15);
    const int brBase = wcn * 64 + (lane & 15);
    const int csw0 = (((lane >> 4)) ^ (lane & 7)) * 8;
    const int csw1 = (((lane >> 4) + 4) ^ (lane & 7)) * 8;

    f32x4 acc[8][4];
#pragma unroll
    for (int m = 0; m < 8; ++m)
#pragma unroll
        for (int n = 0; n < 4; ++n) acc[m][n] = (f32x4){0.f, 0.f, 0.f, 0.f};

#define STAGE_A(bufw, r0, kc)                                                           \
    GLOAD_LDS16(X + ((aGR + (r0) + lrow8) << 10) + (kc) + gchunk * 8,                   \
                &lds[(bufw) + (unsigned)(r0) * 64])
#define STAGE_B(bufw, r0, kc)                                                           \
    GLOAD_LDS16(X + ((bGR + (r0) + lrow8) << 10) + (kc) + gchunk * 8,                   \
                &lds[(bufw) + 16384u + (unsigned)(r0) * 64])

#define LOAD_A(MQ)                                                                      \
    _Pragma("unroll")                                                                   \
    for (int mf = 0; mf < 4; ++mf) {                                                    \
        const unsigned r = bufR + (unsigned)(arBase + (MQ) * 64 + mf * 16) * 64;        \
        aF0[mf] = *reinterpret_cast<const bf16x8*>(&lds[r + csw0]);                     \
        aF1[mf] = *reinterpret_cast<const bf16x8*>(&lds[r + csw1]);                     \
    }
#define LOAD_B(NQ)                                                                      \
    _Pragma("unroll")                                                                   \
    for (int nf = 0; nf < 2; ++nf) {                                                    \
        const unsigned r = bufR + 16384u + (unsigned)(brBase + (NQ) * 32 + nf * 16) * 64; \
        bF0[(NQ) * 2 + nf] = *reinterpret_cast<const bf16x8*>(&lds[r + csw0]);          \
        bF1[(NQ) * 2 + nf] = *reinterpret_cast<const bf16x8*>(&lds[r + csw1]);          \
    }
#define MFMA_Q(MQ, NQ)                                                                  \
    _Pragma("unroll")                                                                   \
    for (int mf = 0; mf < 4; ++mf)                                                      \
        _Pragma("unroll")                                                               \
        for (int nf = 0; nf < 2; ++nf) {                                                \
            acc[(MQ) * 4 + mf][(NQ) * 2 + nf] = __builtin_amdgcn_mfma_f32_16x16x32_bf16( \
                aF0[mf], bF0[(NQ) * 2 + nf], acc[(MQ) * 4 + mf][(NQ) * 2 + nf], 0, 0, 0); \
            acc[(MQ) * 4 + mf][(NQ) * 2 + nf] = __builtin_amdgcn_mfma_f32_16x16x32_bf16( \
                aF1[mf], bF1[(NQ) * 2 + nf], acc[(MQ) * 4 + mf][(NQ) * 2 + nf], 0, 0, 0); \
        }

#define BARRIER asm volatile("s_barrier" ::: "memory")
#define VMCNT(N) asm volatile("s_waitcnt vmcnt(" #N ")" ::: "memory")

    // prologue: stage tile 0 units in issue order u0, u2, u3, u1
    STAGE_A(0u, wv * 8, 0);        STAGE_A(0u, 128 + wv * 8, 0);   // u0 (A MQ0)
    STAGE_B(0u, rB0, 0);           STAGE_B(0u, rB1, 0);            // u2 (B NQ0)
    STAGE_B(0u, rB0 + 32, 0);      STAGE_B(0u, rB1 + 32, 0);       // u3 (B NQ1)
    STAGE_A(0u, 64 + wv * 8, 0);   STAGE_A(0u, 192 + wv * 8, 0);   // u1 (A MQ1)
    VMCNT(4);  // u0,u2 retired; entering loop: outstanding = u3,u1(t0) = 4
    BARRIER;

    for (int kt = 0; kt < NT; ++kt) {
        const bool haveNext = (kt + 1) < NT;
        const unsigned bufR = (kt & 1) ? 32768u : 0u;
        const unsigned bufW = ((kt + 1) & 1) ? 32768u : 0u;
        const int kc = (kt + 1) * 64;

        bf16x8 aF0[4], aF1[4], bF0[4], bF1[4];

        // ---- P1: (MQ0,NQ0); stage u0,u2(next) ----
        LOAD_A(0); LOAD_B(0);
        if (haveNext) {
            STAGE_A(bufW, wv * 8, kc); STAGE_A(bufW, 128 + wv * 8, kc);   // u0
            STAGE_B(bufW, rB0, kc);    STAGE_B(bufW, rB1, kc);            // u2
        }
        BARRIER;
        __builtin_amdgcn_s_setprio(1);
        MFMA_Q(0, 0);
        __builtin_amdgcn_s_setprio(0);
        BARRIER;

        // ---- P2: (MQ0,NQ1) ----
        LOAD_B(1);
        BARRIER;
        __builtin_amdgcn_s_setprio(1);
        MFMA_Q(0, 1);
        __builtin_amdgcn_s_setprio(0);
        if (haveNext) { VMCNT(4); } else { VMCNT(0); }  // retire u3,u1(cur)
        BARRIER;

        // ---- P3: (MQ1,NQ0)+(MQ1,NQ1); stage u3,u1(next) ----
        LOAD_A(1);
        if (haveNext) {
            STAGE_B(bufW, rB0 + 32, kc); STAGE_B(bufW, rB1 + 32, kc);     // u3
            STAGE_A(bufW, 64 + wv * 8, kc); STAGE_A(bufW, 192 + wv * 8, kc); // u1
        }
        BARRIER;
        __builtin_amdgcn_s_setprio(1);
        MFMA_Q(1, 0);
        MFMA_Q(1, 1);
        __builtin_amdgcn_s_setprio(0);
        if (haveNext) { VMCNT(4); }  // retire u0,u2(next)
        BARRIER;
    }

    // epilogue: C/D layout col = lane&15, row = (lane>>4)*4 + reg
    const int rbase = by * 256 + wr * 128;
    const int cbase = bx * 256 + wcn * 64;
    unsigned int* rm = rowmax + t * B_N;

    // row-max over this wave's 64 cols (diag excluded)
#pragma unroll
    for (int m = 0; m < 8; ++m) {
#pragma unroll
        for (int r = 0; r < 4; ++r) {
            const int row = rbase + m * 16 + (lane >> 4) * 4 + r;
            float mx = -2.0f;
#pragma unroll
            for (int n = 0; n < 4; ++n) {
                const int col = cbase + n * 16 + (lane & 15);
                float v = acc[m][n][r];
                if (col != row) mx = fmaxf(mx, v);
            }
#pragma unroll
            for (int off = 1; off < 16; off <<= 1) mx = fmaxf(mx, __shfl_xor(mx, off, 64));
            if ((lane & 15) == 0) atomicMax(&rm[row], f2u_ord(mx));
        }
    }
    // col-max over this wave's 128 rows (covers mirrored lower-triangle block)
#pragma unroll
    for (int n = 0; n < 4; ++n) {
        const int col = cbase + n * 16 + (lane & 15);
        float mx = -2.0f;
#pragma unroll
        for (int m = 0; m < 8; ++m)
#pragma unroll
            for (int r = 0; r < 4; ++r) {
                const int row = rbase + m * 16 + (lane >> 4) * 4 + r;
                float v = acc[m][n][r];
                if (col != row) mx = fmaxf(mx, v);
            }
        mx = fmaxf(mx, __shfl_xor(mx, 16, 64));
        mx = fmaxf(mx, __shfl_xor(mx, 32, 64));
        if ((lane >> 4) == 0) atomicMax(&rm[col], f2u_ord(mx));
    }
#undef MFMA_Q
#undef LOAD_A
#undef LOAD_B
#undef STAGE_A
#undef STAGE_B
#undef BARRIER
#undef VMCNT
}

__global__ __launch_bounds__(256) void finish_kernel(const unsigned int* __restrict__ rowmax,
                                                     float* __restrict__ out) {
    __shared__ float sbuf[4];
    float s = 0.f;
    for (int i = threadIdx.x; i < T_N * B_N; i += 256) {
        float m  = u2f_ord(rowmax[i]);
        float d2 = fmaxf(2.0f - 2.0f * m, 0.0f);
        s += logf(sqrtf(d2) + 1e-12f);
    }
#pragma unroll
    for (int off = 32; off; off >>= 1) s += __shfl_xor(s, off, 64);
    const int w = threadIdx.x >> 6;
    if ((threadIdx.x & 63) == 0) sbuf[w] = s;
    __syncthreads();
    if (threadIdx.x == 0) {
        out[0] = -(sbuf[0] + sbuf[1] + sbuf[2] + sbuf[3]) / (float)(T_N * B_N);
    }
}

extern "C" void kernel_launch(void* const* d_in, const int* in_sizes, int n_in,
                              void* d_out, int out_size, void* d_ws, size_t ws_size,
                              hipStream_t stream) {
    const float* in = (const float*)d_in[0];
    unsigned short* xn = (unsigned short*)d_ws;  // 64 MB bf16 [T][B][D]
    unsigned int* rowmax = (unsigned int*)((char*)d_ws + (size_t)T_N * B_N * D_N * 2);
    float* out = (float*)d_out;

    init_rowmax_kernel<<<(T_N * B_N + 255) / 256, 256, 0, stream>>>(rowmax);
    norm_kernel<<<(B_N * T_N) / 4, 256, 0, stream>>>(in, xn);
    dim3 g(TRI, 1, T_N);
    gemm_rowmax_kernel<<<g, 512, 0, stream>>>(xn, rowmax);
    finish_kernel<<<1, 256, 0, stream>>>(rowmax, out);
}

// Round 6
// 429.000 us; speedup vs baseline: 1.0067x; 1.0067x over previous
//
#include <hip/hip_runtime.h>
#include <hip/hip_bf16.h>
#include <math.h>

#define B_N 8192
#define T_N 4
#define D_N 1024
#define NB  32                 // 8192/256 row/col blocks
#define NT  16                 // 1024/64 K-tiles
#define TRI (NB * (NB + 1) / 2)  // 528 upper-triangle blocks per view (528 = 8*66)

typedef __bf16 bf16x8 __attribute__((ext_vector_type(8)));
typedef float f32x4 __attribute__((ext_vector_type(4)));

// ---- order-preserving float <-> uint map ----
__device__ inline unsigned int f2u_ord(float f) {
    unsigned int b = __float_as_uint(f);
    return (b & 0x80000000u) ? ~b : (b | 0x80000000u);
}
__device__ inline float u2f_ord(unsigned int u) {
    unsigned int b = (u & 0x80000000u) ? (u & 0x7FFFFFFFu) : ~u;
    return __uint_as_float(b);
}

// round-to-nearest-even f32 -> bf16
__device__ inline unsigned short f2bf(float f) {
    unsigned int u = __float_as_uint(f);
    unsigned int r = (u + 0x7FFFu + ((u >> 16) & 1u)) >> 16;
    return (unsigned short)r;
}

__global__ __launch_bounds__(256) void init_rowmax_kernel(unsigned int* __restrict__ rowmax) {
    int i = blockIdx.x * 256 + threadIdx.x;
    if (i < T_N * B_N) rowmax[i] = 0u;
}

// in: [B][T][D] f32 ; out xn: [T][B][D] bf16 (normalized rows)
__global__ __launch_bounds__(256) void norm_kernel(const float* __restrict__ in,
                                                   unsigned short* __restrict__ xn) {
    const int row  = blockIdx.x * 4 + (threadIdx.x >> 6);
    const int lane = threadIdx.x & 63;
    const int b = row >> 2;
    const int t = row & 3;
    const float* src = in + (size_t)row * D_N;

    float4 v[4];
    float ss = 0.f;
#pragma unroll
    for (int i = 0; i < 4; ++i) {
        v[i] = reinterpret_cast<const float4*>(src)[lane + 64 * i];
        ss += v[i].x * v[i].x + v[i].y * v[i].y + v[i].z * v[i].z + v[i].w * v[i].w;
    }
#pragma unroll
    for (int off = 32; off; off >>= 1) ss += __shfl_xor(ss, off, 64);
    const float rn = 1.0f / fmaxf(sqrtf(ss), 1e-12f);

    unsigned short* dst = xn + ((size_t)t * B_N + b) * D_N;
#pragma unroll
    for (int i = 0; i < 4; ++i) {
        ushort4 o;
        o.x = f2bf(v[i].x * rn);
        o.y = f2bf(v[i].y * rn);
        o.z = f2bf(v[i].z * rn);
        o.w = f2bf(v[i].w * rn);
        reinterpret_cast<ushort4*>(dst)[lane + 64 * i] = o;
    }
}

#define GLOAD_LDS16(g, l)                                                              \
    __builtin_amdgcn_global_load_lds(                                                  \
        (const __attribute__((address_space(1))) unsigned int*)(g),                    \
        (__attribute__((address_space(3))) unsigned int*)(l), 16, 0, 0)

// Gram matrix upper-triangle, 256x256 tile, BK=64, 8 waves (2M x 4N).
// Minimal-barrier schedule: 2 {vmcnt+barrier} per K-tile, each followed by one
// big straight-line region {4 stage gloads | 12-16 ds_read_b128 | 32 MFMA} that
// the compiler software-pipelines (fine-grained lgkmcnt), overlapping the LDS
// pipe with the MFMA pipe. Counted gates: entry vmcnt(2) -> A0,B0,B1(cur);
// mid vmcnt(4) -> A1(cur). Stage order per tile: A0',B0' (region1), B1',A1'
// (region2). LDS chunk-XOR swizzle (chunk ^= row&7) source-side + read-side.
__global__ __launch_bounds__(512, 2) void gemm_rowmax_kernel(const unsigned short* __restrict__ xn,
                                                             unsigned int* __restrict__ rowmax) {
    const int t = blockIdx.z;
    // XCD-chunked bijective swizzle: 528 = 8 * 66; consecutive triangle ids
    // (sharing the A row-panel) land on the SAME XCD's L2.
    const int bid = blockIdx.x;
    int l = (bid & 7) * (TRI / 8) + (bid >> 3);
    // triangle decode: linear -> (by, bx), bx >= by
    int by = 0;
    while (l >= NB - by) { l -= NB - by; ++by; }
    const int bx = by + l;

    const unsigned short* X = xn + (size_t)t * B_N * D_N;

    __shared__ __align__(16) unsigned short lds[65536];  // 128 KiB: [2 buf][A 16K el | B 16K el]

    const int tid  = threadIdx.x;
    const int lane = tid & 63;
    const int wv   = tid >> 6;   // 0..7
    const int wr   = wv >> 2;    // M half (128 rows)
    const int wcn  = wv & 3;     // N quarter (64 cols)

    // staging: wave-load = 8 rows x 8 chunks(16B); source chunk pre-swizzled
    const int lrow8  = lane >> 3;
    const int gchunk = (lane & 7) ^ lrow8;
    const size_t aGR = (size_t)by * 256;
    const size_t bGR = (size_t)bx * 256;
    const int idx0 = wv * 2, idx1 = wv * 2 + 1;
    const int rB0 = (idx0 >> 2) * 64 + (idx0 & 3) * 8;
    const int rB1 = (idx1 >> 2) * 64 + (idx1 & 3) * 8;

    // fragment read bases; read-side swizzle: chunk = kk ^ (row&7), row&7 == lane&7
    const int arBase = wr * 128 + (lane & 15);
    const int brBase = wcn * 64 + (lane & 15);
    const int csw0 = (((lane >> 4)) ^ (lane & 7)) * 8;
    const int csw1 = (((lane >> 4) + 4) ^ (lane & 7)) * 8;

    f32x4 acc[8][4];
#pragma unroll
    for (int m = 0; m < 8; ++m)
#pragma unroll
        for (int n = 0; n < 4; ++n) acc[m][n] = (f32x4){0.f, 0.f, 0.f, 0.f};

#define STAGE_A(bufw, r0, kc)                                                           \
    GLOAD_LDS16(X + ((aGR + (r0) + lrow8) << 10) + (kc) + gchunk * 8,                   \
                &lds[(bufw) + (unsigned)(r0) * 64])
#define STAGE_B(bufw, r0, kc)                                                           \
    GLOAD_LDS16(X + ((bGR + (r0) + lrow8) << 10) + (kc) + gchunk * 8,                   \
                &lds[(bufw) + 16384u + (unsigned)(r0) * 64])

#define LOAD_A(MQ)                                                                      \
    _Pragma("unroll")                                                                   \
    for (int mf = 0; mf < 4; ++mf) {                                                    \
        const unsigned r = bufR + (unsigned)(arBase + (MQ) * 64 + mf * 16) * 64;        \
        aF0[mf] = *reinterpret_cast<const bf16x8*>(&lds[r + csw0]);                     \
        aF1[mf] = *reinterpret_cast<const bf16x8*>(&lds[r + csw1]);                     \
    }
#define LOAD_B(NQ)                                                                      \
    _Pragma("unroll")                                                                   \
    for (int nf = 0; nf < 2; ++nf) {                                                    \
        const unsigned r = bufR + 16384u + (unsigned)(brBase + (NQ) * 32 + nf * 16) * 64; \
        bF0[(NQ) * 2 + nf] = *reinterpret_cast<const bf16x8*>(&lds[r + csw0]);          \
        bF1[(NQ) * 2 + nf] = *reinterpret_cast<const bf16x8*>(&lds[r + csw1]);          \
    }
#define MFMA_Q(MQ, NQ)                                                                  \
    _Pragma("unroll")                                                                   \
    for (int mf = 0; mf < 4; ++mf)                                                      \
        _Pragma("unroll")                                                               \
        for (int nf = 0; nf < 2; ++nf) {                                                \
            acc[(MQ) * 4 + mf][(NQ) * 2 + nf] = __builtin_amdgcn_mfma_f32_16x16x32_bf16( \
                aF0[mf], bF0[(NQ) * 2 + nf], acc[(MQ) * 4 + mf][(NQ) * 2 + nf], 0, 0, 0); \
            acc[(MQ) * 4 + mf][(NQ) * 2 + nf] = __builtin_amdgcn_mfma_f32_16x16x32_bf16( \
                aF1[mf], bF1[(NQ) * 2 + nf], acc[(MQ) * 4 + mf][(NQ) * 2 + nf], 0, 0, 0); \
        }

#define BARRIER asm volatile("s_barrier" ::: "memory")
#define VMCNT(N) asm volatile("s_waitcnt vmcnt(" #N ")" ::: "memory")
#define LGKM0 asm volatile("s_waitcnt lgkmcnt(0)" ::: "memory")

    // prologue: stage tile 0 halves in order A0, B0, B1, A1
    STAGE_A(0u, wv * 8, 0);        STAGE_A(0u, 128 + wv * 8, 0);   // A0
    STAGE_B(0u, rB0, 0);           STAGE_B(0u, rB1, 0);            // B0
    STAGE_B(0u, rB0 + 32, 0);      STAGE_B(0u, rB1 + 32, 0);       // B1
    STAGE_A(0u, 64 + wv * 8, 0);   STAGE_A(0u, 192 + wv * 8, 0);   // A1

    for (int kt = 0; kt < NT; ++kt) {
        const bool haveNext = (kt + 1) < NT;
        const unsigned bufR = (kt & 1) ? 32768u : 0u;
        const unsigned bufW = ((kt + 1) & 1) ? 32768u : 0u;
        const int kc = (kt + 1) * 64;

        // tile entry: A0,B0,B1(kt) staged (wave-local count), my reads of bufW
        // (issued last tile) retired, then global join.
        VMCNT(2);
        LGKM0;
        BARRIER;

        bf16x8 aF0[4], aF1[4], bF0[4], bF1[4];

        // ---- region 1: stage A0',B0'; read A0,B0,B1; MFMA (MQ0,*) ----
        if (haveNext) {
            STAGE_A(bufW, wv * 8, kc); STAGE_A(bufW, 128 + wv * 8, kc);   // A0'
            STAGE_B(bufW, rB0, kc);    STAGE_B(bufW, rB1, kc);            // B0'
        }
        LOAD_A(0); LOAD_B(0); LOAD_B(1);
        __builtin_amdgcn_s_setprio(1);
        MFMA_Q(0, 0);
        MFMA_Q(0, 1);
        __builtin_amdgcn_s_setprio(0);

        // mid gate: A1(kt) staged (oldest 2 outstanding), global join
        if (haveNext) { VMCNT(4); } else { VMCNT(0); }
        BARRIER;

        // ---- region 2: stage B1',A1'; read A1; MFMA (MQ1,*) ----
        if (haveNext) {
            STAGE_B(bufW, rB0 + 32, kc); STAGE_B(bufW, rB1 + 32, kc);     // B1'
            STAGE_A(bufW, 64 + wv * 8, kc); STAGE_A(bufW, 192 + wv * 8, kc); // A1'
        }
        LOAD_A(1);
        __builtin_amdgcn_s_setprio(1);
        MFMA_Q(1, 0);
        MFMA_Q(1, 1);
        __builtin_amdgcn_s_setprio(0);
    }

    // epilogue: C/D layout col = lane&15, row = (lane>>4)*4 + reg
    const int rbase = by * 256 + wr * 128;
    const int cbase = bx * 256 + wcn * 64;
    unsigned int* rm = rowmax + t * B_N;

    // row-max over this wave's 64 cols (diag excluded)
#pragma unroll
    for (int m = 0; m < 8; ++m) {
#pragma unroll
        for (int r = 0; r < 4; ++r) {
            const int row = rbase + m * 16 + (lane >> 4) * 4 + r;
            float mx = -2.0f;
#pragma unroll
            for (int n = 0; n < 4; ++n) {
                const int col = cbase + n * 16 + (lane & 15);
                float v = acc[m][n][r];
                if (col != row) mx = fmaxf(mx, v);
            }
#pragma unroll
            for (int off = 1; off < 16; off <<= 1) mx = fmaxf(mx, __shfl_xor(mx, off, 64));
            if ((lane & 15) == 0) atomicMax(&rm[row], f2u_ord(mx));
        }
    }
    // col-max over this wave's 128 rows (covers mirrored lower-triangle block)
#pragma unroll
    for (int n = 0; n < 4; ++n) {
        const int col = cbase + n * 16 + (lane & 15);
        float mx = -2.0f;
#pragma unroll
        for (int m = 0; m < 8; ++m)
#pragma unroll
            for (int r = 0; r < 4; ++r) {
                const int row = rbase + m * 16 + (lane >> 4) * 4 + r;
                float v = acc[m][n][r];
                if (col != row) mx = fmaxf(mx, v);
            }
        mx = fmaxf(mx, __shfl_xor(mx, 16, 64));
        mx = fmaxf(mx, __shfl_xor(mx, 32, 64));
        if ((lane >> 4) == 0) atomicMax(&rm[col], f2u_ord(mx));
    }
#undef MFMA_Q
#undef LOAD_A
#undef LOAD_B
#undef STAGE_A
#undef STAGE_B
#undef BARRIER
#undef VMCNT
#undef LGKM0
}

__global__ __launch_bounds__(256) void finish_kernel(const unsigned int* __restrict__ rowmax,
                                                     float* __restrict__ out) {
    __shared__ float sbuf[4];
    float s = 0.f;
    for (int i = threadIdx.x; i < T_N * B_N; i += 256) {
        float m  = u2f_ord(rowmax[i]);
        float d2 = fmaxf(2.0f - 2.0f * m, 0.0f);
        s += logf(sqrtf(d2) + 1e-12f);
    }
#pragma unroll
    for (int off = 32; off; off >>= 1) s += __shfl_xor(s, off, 64);
    const int w = threadIdx.x >> 6;
    if ((threadIdx.x & 63) == 0) sbuf[w] = s;
    __syncthreads();
    if (threadIdx.x == 0) {
        out[0] = -(sbuf[0] + sbuf[1] + sbuf[2] + sbuf[3]) / (float)(T_N * B_N);
    }
}

extern "C" void kernel_launch(void* const* d_in, const int* in_sizes, int n_in,
                              void* d_out, int out_size, void* d_ws, size_t ws_size,
                              hipStream_t stream) {
    const float* in = (const float*)d_in[0];
    unsigned short* xn = (unsigned short*)d_ws;  // 64 MB bf16 [T][B][D]
    unsigned int* rowmax = (unsigned int*)((char*)d_ws + (size_t)T_N * B_N * D_N * 2);
    float* out = (float*)d_out;

    init_rowmax_kernel<<<(T_N * B_N + 255) / 256, 256, 0, stream>>>(rowmax);
    norm_kernel<<<(B_N * T_N) / 4, 256, 0, stream>>>(in, xn);
    dim3 g(TRI, 1, T_N);
    gemm_rowmax_kernel<<<g, 512, 0, stream>>>(xn, rowmax);
    finish_kernel<<<1, 256, 0, stream>>>(rowmax, out);
}